// Round 9
// baseline (246.416 us; speedup 1.0000x reference)
//
#include <hip/hip_runtime.h>

// LSTM fused kernel for MI355X (gfx950) — round 9.
// B=4096, S=256, H=64, input dim 4 (from Linear(1->4)+tanh).
// = round-6 kernel (185 us best: grid 256, TB=16, 4 waves, gx+bias folded
//   into MFMA, LOG2E pre-scaled weights)
// + round-8's PROVEN fused-rcp cell (7 trans/cell instead of 10; absmax
//   unchanged 4.88e-4) with +-30 clamps
// + per-tile MFMA chain split 7 -> 5+2 (8 independent chains feed the
//   matrix pipe; 1 wave/SIMD so chain latency is otherwise exposed).

typedef __attribute__((ext_vector_type(8))) __bf16 bf16x8;
typedef __attribute__((ext_vector_type(4))) float f32x4;

#define S_LEN 256
#define TB 16
#define CHUNK 64
#define LOG2E 1.4426950408889634f
#define TWO_LOG2E 2.8853900817779268f

#if defined(__has_builtin) && __has_builtin(__builtin_amdgcn_exp2f)
#define EXP2F(x) __builtin_amdgcn_exp2f(x)
#else
#define EXP2F(x) exp2f(x)
#endif
#if defined(__has_builtin) && __has_builtin(__builtin_amdgcn_rcpf)
#define RCPF(x) __builtin_amdgcn_rcpf(x)
#else
#define RCPF(x) (1.0f / (x))
#endif

__device__ __forceinline__ float clamp30(float x) {
    return fminf(fmaxf(x, -30.0f), 30.0f);   // v_med3_f32
}
__device__ __forceinline__ float fast_tanh(float x) {
    float e = EXP2F(TWO_LOG2E * x);
    return 1.0f - 2.0f * RCPF(e + 1.0f);
}

#define MFMA16(A, B, C) __builtin_amdgcn_mfma_f32_16x16x32_bf16((A), (B), (C), 0, 0, 0)

// One LSTM step: read h from buffer RB, write h to buffer WB. TLOC = t & 63.
#define STEP(RB, WB, TLOC) do {                                                   \
    bf16x8 ah0 = *(const bf16x8*)&hbuf[RB][0][0][kg][col][0];                     \
    bf16x8 ah1 = *(const bf16x8*)&hbuf[RB][0][1][kg][col][0];                     \
    bf16x8 al0 = *(const bf16x8*)&hbuf[RB][1][0][kg][col][0];                     \
    bf16x8 al1 = *(const bf16x8*)&hbuf[RB][1][1][kg][col][0];                     \
    bf16x8 fa  = *(const bf16x8*)&fcfrag[TLOC][col][0];                           \
    if (kg >= 2) fa = zero8;                                                      \
    f32x4 acc[4];                                                                 \
    _Pragma("unroll")                                                             \
    for (int n = 0; n < 4; ++n) {                                                 \
        f32x4 a = MFMA16(fa,  whx[n],      biasq[n]);  /* gx + bias (exact) */    \
        a       = MFMA16(ah0, whh_h[n][0], a);                                    \
        a       = MFMA16(ah1, whh_h[n][1], a);                                    \
        a       = MFMA16(ah0, whh_l[n][0], a);                                    \
        a       = MFMA16(ah1, whh_l[n][1], a);                                    \
        f32x4 b = MFMA16(al0, whh_h[n][0], z4);        /* independent chain */    \
        b       = MFMA16(al1, whh_h[n][1], b);                                    \
        acc[n] = a + b;                                                           \
    }                                                                             \
    _Pragma("unroll")                                                             \
    for (int r = 0; r < 4; ++r) {                                                 \
        /* fused-rcp cell (preacts pre-scaled: LOG2E, g-gate 2*LOG2E) */          \
        float Ai = clamp30(acc[0][r]);                                            \
        float Ff = clamp30(acc[1][r]);                                            \
        float Gg = clamp30(acc[2][r]);                                            \
        float Oo = clamp30(acc[3][r]);                                            \
        float ea = EXP2F(-Ai), ef = EXP2F(-Ff), eg = EXP2F(Gg), eo = EXP2F(-Oo);  \
        float tf  = 1.0f + ef;                                                    \
        float tag = (1.0f + ea) * (1.0f + eg);                                    \
        float Nn  = fmaf(cst[r], tag, (eg - 1.0f) * tf);                          \
        float cn  = Nn * RCPF(tag * tf);                                          \
        cst[r] = cn;                                                              \
        float ec  = EXP2F(clamp30(TWO_LOG2E * cn));                               \
        float hvv = (ec - 1.0f) * RCPF((1.0f + eo) * (ec + 1.0f));                \
        hlast[r] = hvv;                                                           \
        __bf16 hh = (__bf16)hvv; __bf16 hl = (__bf16)(hvv - (float)hh);           \
        hbuf[WB][0][uks][ukg][kg * 4 + r][up] = hh;                               \
        hbuf[WB][1][uks][ukg][kg * 4 + r][up] = hl;                               \
    }                                                                             \
    __syncthreads();                                                              \
} while (0)

__global__ __launch_bounds__(256, 1)
void lstm_fused(const float* __restrict__ x,
                const float* __restrict__ W1, const float* __restrict__ b1,
                const float* __restrict__ W_ih, const float* __restrict__ W_hh,
                const float* __restrict__ b_ih, const float* __restrict__ b_hh,
                const float* __restrict__ W2, const float* __restrict__ b2,
                float* __restrict__ out)
{
    // fc1 A-fragments, frag-ready: [t][row][ f_hi(4) | f_lo(4) ]  (16 KB)
    __shared__ __bf16 fcfrag[CHUNK][TB][8];
    // h double buffer, split hi/lo, k-grouped: [buf][hl][ks][kg][row][j] (16 KB)
    __shared__ __bf16 hbuf[2][2][2][4][TB][8];
    // final h for output projection  (4 KB)
    __shared__ float hfin[64][TB];

    const int tid  = threadIdx.x;
    const int lane = tid & 63;
    const int wv   = tid >> 6;     // wave 0..3
    const int col  = lane & 15;    // A-row / D-col
    const int kg   = lane >> 4;    // k-group 0..3
    const int b0   = blockIdx.x * TB;

    const f32x4 z4 = {0.f, 0.f, 0.f, 0.f};

    // ---- weights (LOG2E-pre-scaled), resident in VGPRs ----
    bf16x8 whh_h[4][2], whh_l[4][2];  // W_hh hi/lo per tile/kstep
    bf16x8 whx[4];                    // gx B-frag: kg0=[Whi|Whi], kg1=[Wlo|Wlo], else 0
    f32x4  biasq[4];                  // scaled bias splat (MFMA C-input)

    bf16x8 zero8;
    #pragma unroll
    for (int j = 0; j < 8; ++j) zero8[j] = (__bf16)0.0f;

    #pragma unroll
    for (int n = 0; n < 4; ++n) {
        const int g = 16 * (wv + 4 * n) + col;          // n: 0=i,1=f,2=g,3=o
        const float sc = (n == 2) ? TWO_LOG2E : LOG2E;
        #pragma unroll
        for (int ks = 0; ks < 2; ++ks) {
            const float* wp = &W_hh[g * 64 + ks * 32 + kg * 8];
            #pragma unroll
            for (int j = 0; j < 8; ++j) {
                float wf  = sc * wp[j];
                __bf16 hi = (__bf16)wf;
                whh_h[n][ks][j] = hi;
                whh_l[n][ks][j] = (__bf16)(wf - (float)hi);
            }
        }
        whx[n] = zero8;
        if (kg < 2) {
            #pragma unroll
            for (int j = 0; j < 4; ++j) {
                float wf  = sc * W_ih[g * 4 + j];
                __bf16 hi = (__bf16)wf;
                __bf16 v  = (kg == 0) ? hi : (__bf16)(wf - (float)hi);
                whx[n][j] = v; whx[n][j + 4] = v;
            }
        }
        const float bs = sc * (b_ih[g] + b_hh[g]);
        biasq[n][0] = bs; biasq[n][1] = bs; biasq[n][2] = bs; biasq[n][3] = bs;
    }

    // zero h0 (buffer 0 = first 4 KB of hbuf)
    {
        f32x4 zv = {0.f, 0.f, 0.f, 0.f};
        ((f32x4*)&hbuf[0][0][0][0][0][0])[tid] = zv;
    }

    float w1r[4], b1r[4];
    #pragma unroll
    for (int j = 0; j < 4; ++j) { w1r[j] = W1[j]; b1r[j] = b1[j]; }

    float cst[4] = {0.f, 0.f, 0.f, 0.f};
    float hlast[4];

    const int u   = 16 * wv + col;    // this lane's h-unit
    const int uks = u >> 5, ukg = (u >> 3) & 3, up = u & 7;

    for (int t = 0; t < S_LEN; t += 2) {
        if ((t & (CHUNK - 1)) == 0) {
            __syncthreads();   // prior chunk's fcfrag reads done (covers init at t=0)
            const int rr = tid & 15;
            const int tq = tid >> 4;         // 0..15, 4 steps each
            f32x4 xv = *(const f32x4*)&x[(b0 + rr) * S_LEN + t + tq * 4];
            #pragma unroll
            for (int tl = 0; tl < 4; ++tl) {
                bf16x8 v;
                #pragma unroll
                for (int j = 0; j < 4; ++j) {
                    float fc  = fast_tanh(xv[tl] * w1r[j] + b1r[j]);
                    __bf16 hi = (__bf16)fc;
                    v[j]     = hi;
                    v[j + 4] = (__bf16)(fc - (float)hi);
                }
                *(bf16x8*)&fcfrag[tq * 4 + tl][rr][0] = v;
            }
            __syncthreads();
        }
        STEP(0, 1, (t & (CHUNK - 1)));
        STEP(1, 0, ((t + 1) & (CHUNK - 1)));
    }

    // epilogue: out[b] = h_last . W2 + b2
    #pragma unroll
    for (int r = 0; r < 4; ++r) hfin[u][kg * 4 + r] = hlast[r];
    __syncthreads();
    if (tid < TB) {
        float s = b2[0];
        #pragma unroll
        for (int uu = 0; uu < 64; ++uu) s += hfin[uu][tid] * W2[uu];
        out[b0 + tid] = s;
    }
}

extern "C" void kernel_launch(void* const* d_in, const int* in_sizes, int n_in,
                              void* d_out, int out_size, void* d_ws, size_t ws_size,
                              hipStream_t stream) {
    (void)in_sizes; (void)n_in; (void)d_ws; (void)ws_size; (void)out_size;
    const float* x    = (const float*)d_in[0];
    const float* W1   = (const float*)d_in[1];
    const float* b1   = (const float*)d_in[2];
    const float* W_ih = (const float*)d_in[3];
    const float* W_hh = (const float*)d_in[4];
    const float* b_ih = (const float*)d_in[5];
    const float* b_hh = (const float*)d_in[6];
    const float* W2   = (const float*)d_in[7];
    const float* b2   = (const float*)d_in[8];
    float* out = (float*)d_out;
    lstm_fused<<<4096 / TB, 256, 0, stream>>>(x, W1, b1, W_ih, W_hh, b_ih, b_hh, W2, b2, out);
}